// Round 17
// baseline (947.939 us; speedup 1.0000x reference)
//
#include <hip/hip_runtime.h>

#define NN 100000
#define HH 128
#define EE 600000
#define LL 2
#define RR 3
#define AAA 64
#define CC 16
#define SCAN_B 98   // 98 blocks x 1024 elems covers 100000
#define ATTN_GRID ((NN + 127) / 128)

typedef unsigned short u16;
typedef unsigned int u32;
typedef __attribute__((ext_vector_type(8))) short bf16x8;
typedef __attribute__((ext_vector_type(4))) float f32x4;

__device__ inline u16 f2bf(float f) {   // RNE f32 -> bf16
    unsigned int u = __float_as_uint(f);
    return (u16)((u + 0x7FFF + ((u >> 16) & 1)) >> 16);
}
__device__ inline float bf2f(u16 h) { return __uint_as_float((unsigned int)h << 16); }

// Packed X layout (per row: 512B, 4 chunks of 128B; chunk = 4 groups of [16B hi][16B lo],
// XOR-swizzled by row). row0 % 128 == 0 so block-local r has same r&7 as global row.
__device__ __forceinline__ int hi_off(int gi, int r) { return (gi * 32) ^ ((r & 7) << 4); }
__device__ __forceinline__ int lo_off(int gi, int r) { return (gi * 32 + 16) ^ ((r & 7) << 4); }

// async global->LDS, 16B per lane; dest must be linear (wave-uniform base + lane*16)
__device__ __forceinline__ void stage16(const void* g, void* l) {
    __builtin_amdgcn_global_load_lds((const __attribute__((address_space(1))) unsigned int*)g,
                                     (__attribute__((address_space(3))) unsigned int*)l, 16, 0, 0);
}

// ---------------- weight fusion: W transposed [n][k], split bf16 hi/lo ----------------
__global__ void k_fuse_w(const float* __restrict__ Wsrc, const float* __restrict__ Wdst,
                         const float* __restrict__ Wupd, u16* __restrict__ Wdt_hi,
                         u16* __restrict__ Wdt_lo, u16* __restrict__ Wst_hi,
                         u16* __restrict__ Wst_lo) {
    int b = blockIdx.x;
    int lr = b >> 7, i = b & 127;   // i = k index
    int t = threadIdx.x;
    int j = t & 127;                // j = n index
    const float* wu = Wupd + (size_t)lr * 2 * HH * HH;
    float acc = 0.f;
    size_t o = ((size_t)lr * HH + j) * HH + i;  // transposed store [n=j][k=i]
    if (t < 128) {
        const float* wd = Wdst + ((size_t)lr * HH + i) * HH;
        for (int k = 0; k < HH; ++k) acc += wd[k] * wu[k * HH + j];
        u16 h = f2bf(acc);
        Wdt_hi[o] = h;
        Wdt_lo[o] = f2bf(acc - bf2f(h));
    } else {
        const float* wsc = Wsrc + ((size_t)lr * HH + i) * HH;
        for (int k = 0; k < HH; ++k) acc += wsc[k] * wu[(HH + k) * HH + j];
        u16 h = f2bf(acc);
        Wst_hi[o] = h;
        Wst_lo[o] = f2bf(acc - bf2f(h));
    }
}

__global__ void k_fuse_b(const float* __restrict__ bsrc, const float* __restrict__ bdst,
                         const float* __restrict__ bupd, const float* __restrict__ Wupd,
                         float* __restrict__ fB) {
    int lr = blockIdx.x;
    int j = threadIdx.x;
    const float* wu = Wupd + (size_t)lr * 2 * HH * HH;
    const float* bd = bdst + lr * HH;
    const float* bs = bsrc + lr * HH;
    float acc = bupd[lr * HH + j];
    for (int k = 0; k < HH; ++k)
        acc += bd[k] * wu[k * HH + j] + bs[k] * wu[(HH + k) * HH + j];
    fB[lr * HH + j] = acc;
}

// attnW1 [L][H][A] -> transposed [L][A][H] bf16 hi/lo (for MFMA B-frags)
__global__ void k_fuse_a(const float* __restrict__ W1, u16* __restrict__ Ah,
                         u16* __restrict__ Al) {
    int b = blockIdx.x;            // l*AAA + a
    int l = b >> 6, a = b & 63;
    int k = threadIdx.x;           // 128 threads
    float v = W1[((size_t)l * HH + k) * AAA + a];
    u16 h = f2bf(v);
    size_t o = (size_t)b * HH + k;
    Ah[o] = h;
    Al[o] = f2bf(v - bf2f(h));
}

// ---------------- CSR build: batched over 3 relations; count stores per-edge slot ----------------
__global__ void k_count(const int* __restrict__ e0, const int* __restrict__ e1,
                        const int* __restrict__ e2, int* __restrict__ cnt,
                        int* __restrict__ pose) {
    int rel = blockIdx.y;
    const int* d = (rel == 0 ? e0 : rel == 1 ? e1 : e2) + EE;
    int i = blockIdx.x * 256 + threadIdx.x;
    if (i < EE) pose[rel * EE + i] = atomicAdd(&cnt[rel * NN + d[i]], 1);
}

__global__ void k_scan1(const int* __restrict__ cnt_all, int* __restrict__ rs_all,
                        int* __restrict__ bsum) {
    __shared__ int sd[256];
    int rel = blockIdx.y;
    const int* cnt = cnt_all + rel * NN;
    int* rs = rs_all + rel * NN;
    int blk = blockIdx.x, tid = threadIdx.x;
    int base = blk * 1024 + tid * 4;
    int c0 = 0, c1 = 0, c2 = 0, c3 = 0;
    if (base + 0 < NN) c0 = cnt[base + 0];
    if (base + 1 < NN) c1 = cnt[base + 1];
    if (base + 2 < NN) c2 = cnt[base + 2];
    if (base + 3 < NN) c3 = cnt[base + 3];
    int s = c0 + c1 + c2 + c3;
    sd[tid] = s;
    __syncthreads();
    for (int off = 1; off < 256; off <<= 1) {
        int v = (tid >= off) ? sd[tid - off] : 0;
        __syncthreads();
        sd[tid] += v;
        __syncthreads();
    }
    int excl = sd[tid] - s;
    if (tid == 255) bsum[rel * 128 + blk] = sd[255];
    if (base + 0 < NN) rs[base + 0] = excl;
    if (base + 1 < NN) rs[base + 1] = excl + c0;
    if (base + 2 < NN) rs[base + 2] = excl + c0 + c1;
    if (base + 3 < NN) rs[base + 3] = excl + c0 + c1 + c2;
}

__global__ void k_scan2(int* __restrict__ bsum) {  // grid = 3, 128 threads
    __shared__ int sd[128];
    int rel = blockIdx.x;
    int tid = threadIdx.x;
    int v = (tid < SCAN_B) ? bsum[rel * 128 + tid] : 0;
    sd[tid] = v;
    __syncthreads();
    for (int off = 1; off < 128; off <<= 1) {
        int u = (tid >= off) ? sd[tid - off] : 0;
        __syncthreads();
        sd[tid] += u;
        __syncthreads();
    }
    if (tid < SCAN_B) bsum[rel * 128 + tid] = sd[tid] - v;  // exclusive
}

__global__ void k_scan3(int* __restrict__ rs_all, const int* __restrict__ bsum) {
    int rel = blockIdx.y;
    int i = blockIdx.x * 256 + threadIdx.x;
    if (i < NN) rs_all[rel * NN + i] += bsum[rel * 128 + (i >> 10)];
}

// atomic-free scatter: slot precomputed by k_count
__global__ void k_fill(const int* __restrict__ e0, const int* __restrict__ e1,
                       const int* __restrict__ e2, const int* __restrict__ pose,
                       const int* __restrict__ rs_all, int* __restrict__ csr_all) {
    int rel = blockIdx.y;
    const int* e = rel == 0 ? e0 : rel == 1 ? e1 : e2;
    int i = blockIdx.x * 256 + threadIdx.x;
    if (i >= EE) return;
    int s = e[i], d = e[EE + i];
    csr_all[(size_t)rel * EE + rs_all[rel * NN + d] + pose[rel * EE + i]] = s;
}

// ---------------- aggregation: FOUR nodes per wave (16 lanes/node, 32B/lane) ----------------
// 4-edge batch x 2 float4-loads/edge = 8 loads in flight per node, 32 per wave (4x MLP vs
// 2-node version). Lane l covers bf16-group l (elems 8l..8l+7): chunk l>>2, slot gi=l&3.
// blockIdx.y = y selects {dest, src, bnsc}; relation index = rel0 + y.
__global__ __launch_bounds__(256) void k_aggr(u16* d0, u16* d1, u16* d2,
                                              const float* s0, const float* s1, const float* s2,
                                              const float* bn0, const float* bn1, const float* bn2,
                                              const int* __restrict__ irs, const int* __restrict__ icnt,
                                              const int* __restrict__ icsr, int rel0) {
    int y = blockIdx.y;
    u16* Xp = y == 0 ? d0 : (y == 1 ? d1 : d2);
    const float* xs = y == 0 ? s0 : (y == 1 ? s1 : s2);
    const float* bnsc = y == 0 ? bn0 : (y == 1 ? bn1 : bn2);
    int rel = rel0 + y;
    const int* rs = irs + rel * NN;
    const int* cnt = icnt + rel * NN;
    const int* csr = icsr + (size_t)rel * EE;

    int node = blockIdx.x * 16 + (threadIdx.x >> 4);
    if (node >= NN) return;
    int l = threadIdx.x & 15;
    int beg = rs[node], deg = cnt[node];
    const float4* xs4 = (const float4*)xs;
    bool bn = bnsc != nullptr;
    float4 sca = make_float4(1.f, 1.f, 1.f, 1.f), scb = sca;
    float4 sfa = make_float4(0.f, 0.f, 0.f, 0.f), sfb = sfa;
    if (bn) {
        sca = *(const float4*)&bnsc[l * 8];
        scb = *(const float4*)&bnsc[l * 8 + 4];
        sfa = *(const float4*)&bnsc[128 + l * 8];
        sfb = *(const float4*)&bnsc[128 + l * 8 + 4];
    }
    auto xfa = [&](float4 v) {
        if (bn) {
            v.x = v.x * sca.x + sfa.x; v.y = v.y * sca.y + sfa.y;
            v.z = v.z * sca.z + sfa.z; v.w = v.w * sca.w + sfa.w;
            v.x = v.x >= 0.f ? v.x : 0.01f * v.x;
            v.y = v.y >= 0.f ? v.y : 0.01f * v.y;
            v.z = v.z >= 0.f ? v.z : 0.01f * v.z;
            v.w = v.w >= 0.f ? v.w : 0.01f * v.w;
        }
        return v;
    };
    auto xfb = [&](float4 v) {
        if (bn) {
            v.x = v.x * scb.x + sfb.x; v.y = v.y * scb.y + sfb.y;
            v.z = v.z * scb.z + sfb.z; v.w = v.w * scb.w + sfb.w;
            v.x = v.x >= 0.f ? v.x : 0.01f * v.x;
            v.y = v.y >= 0.f ? v.y : 0.01f * v.y;
            v.z = v.z >= 0.f ? v.z : 0.01f * v.z;
            v.w = v.w >= 0.f ? v.w : 0.01f * v.w;
        }
        return v;
    };
    float4 aA = make_float4(0.f, 0.f, 0.f, 0.f), aB = aA;
    auto addA = [&](float4 v) { aA.x += v.x; aA.y += v.y; aA.z += v.z; aA.w += v.w; };
    auto addB = [&](float4 v) { aB.x += v.x; aB.y += v.y; aB.z += v.z; aB.w += v.w; };
    int j = 0;
    for (; j + 4 <= deg; j += 4) {
        int q0 = csr[beg + j], q1 = csr[beg + j + 1];
        int q2 = csr[beg + j + 2], q3 = csr[beg + j + 3];
        float4 a0 = xfa(xs4[(size_t)q0 * 32 + 2 * l]);
        float4 b0 = xfb(xs4[(size_t)q0 * 32 + 2 * l + 1]);
        float4 a1 = xfa(xs4[(size_t)q1 * 32 + 2 * l]);
        float4 b1 = xfb(xs4[(size_t)q1 * 32 + 2 * l + 1]);
        float4 a2 = xfa(xs4[(size_t)q2 * 32 + 2 * l]);
        float4 b2 = xfb(xs4[(size_t)q2 * 32 + 2 * l + 1]);
        float4 a3 = xfa(xs4[(size_t)q3 * 32 + 2 * l]);
        float4 b3 = xfb(xs4[(size_t)q3 * 32 + 2 * l + 1]);
        aA.x += (a0.x + a1.x) + (a2.x + a3.x);
        aA.y += (a0.y + a1.y) + (a2.y + a3.y);
        aA.z += (a0.z + a1.z) + (a2.z + a3.z);
        aA.w += (a0.w + a1.w) + (a2.w + a3.w);
        aB.x += (b0.x + b1.x) + (b2.x + b3.x);
        aB.y += (b0.y + b1.y) + (b2.y + b3.y);
        aB.z += (b0.z + b1.z) + (b2.z + b3.z);
        aB.w += (b0.w + b1.w) + (b2.w + b3.w);
    }
    if (j + 2 <= deg) {
        int q0 = csr[beg + j], q1 = csr[beg + j + 1];
        float4 a0 = xfa(xs4[(size_t)q0 * 32 + 2 * l]);
        float4 b0 = xfb(xs4[(size_t)q0 * 32 + 2 * l + 1]);
        float4 a1 = xfa(xs4[(size_t)q1 * 32 + 2 * l]);
        float4 b1 = xfb(xs4[(size_t)q1 * 32 + 2 * l + 1]);
        aA.x += a0.x + a1.x; aA.y += a0.y + a1.y;
        aA.z += a0.z + a1.z; aA.w += a0.w + a1.w;
        aB.x += b0.x + b1.x; aB.y += b0.y + b1.y;
        aB.z += b0.z + b1.z; aB.w += b0.w + b1.w;
        j += 2;
    }
    if (j < deg) {
        int q0 = csr[beg + j];
        addA(xfa(xs4[(size_t)q0 * 32 + 2 * l]));
        addB(xfb(xs4[(size_t)q0 * 32 + 2 * l + 1]));
    }
    float sc = 1.0f / fmaxf((float)deg, 1.0f);
    float v0 = aA.x * sc, v1 = aA.y * sc, v2 = aA.z * sc, v3 = aA.w * sc;
    float v4 = aB.x * sc, v5 = aB.y * sc, v6 = aB.z * sc, v7 = aB.w * sc;
    u16 h0 = f2bf(v0), h1 = f2bf(v1), h2 = f2bf(v2), h3 = f2bf(v3);
    u16 h4 = f2bf(v4), h5 = f2bf(v5), h6 = f2bf(v6), h7 = f2bf(v7);
    bf16x8 hv = {(short)h0, (short)h1, (short)h2, (short)h3,
                 (short)h4, (short)h5, (short)h6, (short)h7};
    bf16x8 lv = {(short)f2bf(v0 - bf2f(h0)), (short)f2bf(v1 - bf2f(h1)),
                 (short)f2bf(v2 - bf2f(h2)), (short)f2bf(v3 - bf2f(h3)),
                 (short)f2bf(v4 - bf2f(h4)), (short)f2bf(v5 - bf2f(h5)),
                 (short)f2bf(v6 - bf2f(h6)), (short)f2bf(v7 - bf2f(h7))};
    int gi = l & 3;
    char* base = (char*)Xp + (size_t)node * 512 + (l >> 2) * 128;
    __builtin_nontemporal_store(hv, (bf16x8*)(base + hi_off(gi, node)));
    __builtin_nontemporal_store(lv, (bf16x8*)(base + lo_off(gi, node)));
}

// ---------------- fused conv GEMM, batched over up to 3 relations (blockIdx.y) ----------------
// Y = X1@Wsrc' + X2@Wdst' + bias via bf16x3 MFMA; chunk-level double-buffered LDS.
// X1 packed == Y buffer (in-place). lr = lr0 + y selects weights/bias.
__global__ __launch_bounds__(256) void k_cgemm(float* Y0, float* Y1, float* Y2,
                                               const float* X20, const float* X21, const float* X22,
                                               const u16* __restrict__ Wsh, const u16* __restrict__ Wsl,
                                               const u16* __restrict__ Wdh, const u16* __restrict__ Wdl,
                                               const float* __restrict__ fB, int lr0,
                                               const float* bn0, const float* bn1, const float* bn2,
                                               float* cs0, float* cs1, float* cs2, int nrows) {
    __shared__ __attribute__((aligned(16))) char Xt[2][16384];
    int y = blockIdx.y;
    float* Y = y == 0 ? Y0 : (y == 1 ? Y1 : Y2);
    const u16* X1p = (const u16*)Y;
    const float* X2 = y == 0 ? X20 : (y == 1 ? X21 : X22);
    const float* bnsc2 = y == 0 ? bn0 : (y == 1 ? bn1 : bn2);
    float* colsum = y == 0 ? cs0 : (y == 1 ? cs1 : cs2);
    int lr = lr0 + y;
    const u16* W1h = Wsh + (size_t)lr * HH * HH;
    const u16* W1l = Wsl + (size_t)lr * HH * HH;
    const u16* W2h = Wdh + (size_t)lr * HH * HH;
    const u16* W2l = Wdl + (size_t)lr * HH * HH;
    const float* bias = fB + lr * HH;

    int tid = threadIdx.x;
    int row0 = blockIdx.x * 128;
    int lane = tid & 63, wv = tid >> 6;
    int l15 = lane & 15, lg = lane >> 4;
    bool full = (row0 + 128 <= nrows);

    f32x4 acc[8][2];
#pragma unroll
    for (int i = 0; i < 8; ++i)
#pragma unroll
        for (int j = 0; j < 2; ++j) acc[i][j] = (f32x4)(0.f);

    auto stage_chunk = [&](int c) {
        char* dst = Xt[c & 1];
        if (c < 4) {
#pragma unroll
            for (int p = 0; p < 4; ++p) {
                int tb = p * 4096 + tid * 16;
                int r = tb >> 7, off = tb & 127;
                stage16((const char*)X1p + (size_t)(row0 + r) * 512 + (c & 3) * 128 + off,
                        dst + tb);
            }
        } else {
            int kc = (c & 3) * 32;
#pragma unroll
            for (int it = 0; it < 2; ++it) {
                int g2 = tid + it * 256;
                int r = g2 >> 2, gi = g2 & 3;
                float4 a = make_float4(0.f, 0.f, 0.f, 0.f), b = a;
                if (full || row0 + r < nrows) {
                    const float* xp = &X2[(size_t)(row0 + r) * HH + kc + gi * 8];
                    a = *(const float4*)xp;
                    b = *(const float4*)(xp + 4);
                }
                if (bnsc2) {
                    const float* scp = bnsc2 + kc + gi * 8;
                    const float* sfp = bnsc2 + 128 + kc + gi * 8;
                    float4 s0 = *(const float4*)scp, s1 = *(const float4*)(scp + 4);
                    float4 f0 = *(const float4*)sfp, f1 = *(const float4*)(sfp + 4);
                    a.x = a.x * s0.x + f0.x; a.y = a.y * s0.y + f0.y;
                    a.z = a.z * s0.z + f0.z; a.w = a.w * s0.w + f0.w;
                    b.x = b.x * s1.x + f1.x; b.y = b.y * s1.y + f1.y;
                    b.z = b.z * s1.z + f1.z; b.w = b.w * s1.w + f1.w;
                    a.x = a.x >= 0.f ? a.x : 0.01f * a.x;
                    a.y = a.y >= 0.f ? a.y : 0.01f * a.y;
                    a.z = a.z >= 0.f ? a.z : 0.01f * a.z;
                    a.w = a.w >= 0.f ? a.w : 0.01f * a.w;
                    b.x = b.x >= 0.f ? b.x : 0.01f * b.x;
                    b.y = b.y >= 0.f ? b.y : 0.01f * b.y;
                    b.z = b.z >= 0.f ? b.z : 0.01f * b.z;
                    b.w = b.w >= 0.f ? b.w : 0.01f * b.w;
                }
                u16 h0 = f2bf(a.x), h1 = f2bf(a.y), h2 = f2bf(a.z), h3 = f2bf(a.w);
                u16 h4 = f2bf(b.x), h5 = f2bf(b.y), h6 = f2bf(b.z), h7 = f2bf(b.w);
                bf16x8 hv = {(short)h0, (short)h1, (short)h2, (short)h3,
                             (short)h4, (short)h5, (short)h6, (short)h7};
                bf16x8 lv = {(short)f2bf(a.x - bf2f(h0)), (short)f2bf(a.y - bf2f(h1)),
                             (short)f2bf(a.z - bf2f(h2)), (short)f2bf(a.w - bf2f(h3)),
                             (short)f2bf(b.x - bf2f(h4)), (short)f2bf(b.y - bf2f(h5)),
                             (short)f2bf(b.z - bf2f(h6)), (short)f2bf(b.w - bf2f(h7))};
                char* rb = dst + r * 128;
                *(bf16x8*)(rb + hi_off(gi, r)) = hv;
                *(bf16x8*)(rb + lo_off(gi, r)) = lv;
            }
        }
    };

    stage_chunk(0);
#pragma unroll
    for (int c = 0; c < 8; ++c) {
        const u16* Wh = (c < 4) ? W1h : W2h;
        const u16* Wl = (c < 4) ? W1l : W2l;
        int kc = (c & 3) * 32;
        bf16x8 bh[2], bl[2];
#pragma unroll
        for (int nt = 0; nt < 2; ++nt) {
            int n = (wv * 2 + nt) * 16 + l15;
            bh[nt] = *(const bf16x8*)&Wh[(size_t)n * HH + kc + lg * 8];
            bl[nt] = *(const bf16x8*)&Wl[(size_t)n * HH + kc + lg * 8];
        }
        __syncthreads();  // chunk c staged & chunk c-1 fully consumed
        if (c < 7) stage_chunk(c + 1);  // overlaps with MFMA below
        const char* buf = Xt[c & 1];
#pragma unroll
        for (int mt = 0; mt < 8; ++mt) {
            int r = mt * 16 + l15;
            const char* rb = buf + r * 128;
            bf16x8 ah = *(const bf16x8*)(rb + hi_off(lg, r));
            bf16x8 al = *(const bf16x8*)(rb + lo_off(lg, r));
#pragma unroll
            for (int nt = 0; nt < 2; ++nt) {
                acc[mt][nt] = __builtin_amdgcn_mfma_f32_16x16x32_bf16(ah, bh[nt], acc[mt][nt], 0, 0, 0);
                acc[mt][nt] = __builtin_amdgcn_mfma_f32_16x16x32_bf16(ah, bl[nt], acc[mt][nt], 0, 0, 0);
                acc[mt][nt] = __builtin_amdgcn_mfma_f32_16x16x32_bf16(al, bh[nt], acc[mt][nt], 0, 0, 0);
            }
        }
    }
#pragma unroll
    for (int nt = 0; nt < 2; ++nt) {
        int ncol = (wv * 2 + nt) * 16 + l15;
        float bv = bias[ncol];
        float s = 0.f, q = 0.f;
#pragma unroll
        for (int mt = 0; mt < 8; ++mt)
#pragma unroll
            for (int j = 0; j < 4; ++j) {
                int r = row0 + mt * 16 + lg * 4 + j;
                if (r < nrows) {
                    float yv = acc[mt][nt][j] + bv;
                    Y[(size_t)r * HH + ncol] = yv;
                    s += yv;
                    q += yv * yv;
                }
            }
        if (colsum) {
            s += __shfl_xor(s, 16); s += __shfl_xor(s, 32);
            q += __shfl_xor(q, 16); q += __shfl_xor(q, 32);
            if (lg == 0) {
                atomicAdd(&colsum[ncol], s);
                atomicAdd(&colsum[128 + ncol], q);
            }
        }
    }
}

// ---------------- attention score: bf16x3 MFMA S = X@W1, tanh, dot w2, block-sum ----------------
__global__ __launch_bounds__(256) void k_attn(const float* __restrict__ XA, const float* __restrict__ XB,
                                              const u16* __restrict__ Ah, const u16* __restrict__ Al,
                                              const float* __restrict__ b1, const float* __restrict__ w2,
                                              float* __restrict__ PA, float* __restrict__ PB, int nrows) {
    __shared__ __attribute__((aligned(16))) char Xt[2][16384];
    __shared__ float red[4];
    int tid = threadIdx.x;
    bool second = blockIdx.x >= ATTN_GRID;
    const float* X = second ? XB : XA;
    float* partial = second ? PB : PA;
    int row0 = (second ? blockIdx.x - ATTN_GRID : blockIdx.x) * 128;
    int lane = tid & 63, wv = tid >> 6;
    int l15 = lane & 15, lg = lane >> 4;
    bool full = (row0 + 128 <= nrows);

    f32x4 acc[8];
#pragma unroll
    for (int i = 0; i < 8; ++i) acc[i] = (f32x4)(0.f);

    auto stage_chunk = [&](int c) {
        char* dst = Xt[c & 1];
        int kc = c * 32;
#pragma unroll
        for (int it = 0; it < 2; ++it) {
            int g2 = tid + it * 256;
            int r = g2 >> 2, gi = g2 & 3;
            float4 a = make_float4(0.f, 0.f, 0.f, 0.f), b = a;
            if (full || row0 + r < nrows) {
                const float* xp = &X[(size_t)(row0 + r) * HH + kc + gi * 8];
                a = *(const float4*)xp;
                b = *(const float4*)(xp + 4);
            }
            u16 h0 = f2bf(a.x), h1 = f2bf(a.y), h2 = f2bf(a.z), h3 = f2bf(a.w);
            u16 h4 = f2bf(b.x), h5 = f2bf(b.y), h6 = f2bf(b.z), h7 = f2bf(b.w);
            bf16x8 hv = {(short)h0, (short)h1, (short)h2, (short)h3,
                         (short)h4, (short)h5, (short)h6, (short)h7};
            bf16x8 lv = {(short)f2bf(a.x - bf2f(h0)), (short)f2bf(a.y - bf2f(h1)),
                         (short)f2bf(a.z - bf2f(h2)), (short)f2bf(a.w - bf2f(h3)),
                         (short)f2bf(b.x - bf2f(h4)), (short)f2bf(b.y - bf2f(h5)),
                         (short)f2bf(b.z - bf2f(h6)), (short)f2bf(b.w - bf2f(h7))};
            char* rb = dst + r * 128;
            *(bf16x8*)(rb + hi_off(gi, r)) = hv;
            *(bf16x8*)(rb + lo_off(gi, r)) = lv;
        }
    };

    stage_chunk(0);
#pragma unroll
    for (int c = 0; c < 4; ++c) {
        int kc = c * 32;
        int a = wv * 16 + l15;
        bf16x8 bh = *(const bf16x8*)&Ah[(size_t)a * HH + kc + lg * 8];
        bf16x8 bl = *(const bf16x8*)&Al[(size_t)a * HH + kc + lg * 8];
        __syncthreads();
        if (c < 3) stage_chunk(c + 1);
        const char* buf = Xt[c & 1];
#pragma unroll
        for (int mt = 0; mt < 8; ++mt) {
            int r = mt * 16 + l15;
            const char* rb = buf + r * 128;
            bf16x8 ah = *(const bf16x8*)(rb + hi_off(lg, r));
            bf16x8 al = *(const bf16x8*)(rb + lo_off(lg, r));
            acc[mt] = __builtin_amdgcn_mfma_f32_16x16x32_bf16(ah, bh, acc[mt], 0, 0, 0);
            acc[mt] = __builtin_amdgcn_mfma_f32_16x16x32_bf16(ah, bl, acc[mt], 0, 0, 0);
            acc[mt] = __builtin_amdgcn_mfma_f32_16x16x32_bf16(al, bh, acc[mt], 0, 0, 0);
        }
    }
    float b1v = b1[wv * 16 + l15];
    float w2v = w2[wv * 16 + l15];
    float tot = 0.f;
#pragma unroll
    for (int mt = 0; mt < 8; ++mt)
#pragma unroll
        for (int j = 0; j < 4; ++j) {
            int r = row0 + mt * 16 + lg * 4 + j;
            if (r < nrows) tot += tanhf(acc[mt][j] + b1v) * w2v;
        }
#pragma unroll
    for (int off = 32; off > 0; off >>= 1) tot += __shfl_xor(tot, off);
    if (lane == 0) red[wv] = tot;
    __syncthreads();
    if (tid == 0)
        partial[second ? (blockIdx.x - ATTN_GRID) : blockIdx.x] = red[0] + red[1] + red[2] + red[3];
}

__global__ void k_alpha(const float* __restrict__ P1, const float* __restrict__ P2,
                        float* __restrict__ alpha, int nparts, float invn) {
    __shared__ float s1[256], s2[256];
    int tid = threadIdx.x;
    float a = 0.f, b = 0.f;
    for (int i = tid; i < nparts; i += 256) { a += P1[i]; b += P2[i]; }
    s1[tid] = a; s2[tid] = b;
    __syncthreads();
    for (int off = 128; off > 0; off >>= 1) {
        if (tid < off) { s1[tid] += s1[tid + off]; s2[tid] += s2[tid + off]; }
        __syncthreads();
    }
    if (tid == 0) {
        float m1 = s1[0] * invn, m2 = s2[0] * invn;
        float mx = fmaxf(m1, m2);
        float e1 = expf(m1 - mx), e2 = expf(m2 - mx);
        float inv = 1.f / (e1 + e2);
        alpha[0] = e1 * inv; alpha[1] = e2 * inv;
    }
}

// ---------------- combine (attention mix) + column stats ----------------
__global__ __launch_bounds__(256) void k_comb(float* __restrict__ X, const float* __restrict__ Y,
                                              const float* __restrict__ alpha, float* __restrict__ colsum,
                                              float* __restrict__ colsq, int nrows) {
    int tid = threadIdx.x;
    int h = tid & 127, half = tid >> 7;
    float a0 = alpha[0], a1 = alpha[1];
    float s = 0.f, q = 0.f;
    for (int n = blockIdx.x * 2 + half; n < nrows; n += gridDim.x * 2) {
        size_t off = (size_t)n * HH + h;
        float v = a0 * X[off] + a1 * Y[off];
        X[off] = v;
        s += v; q += v * v;
    }
    __shared__ float ls[256], lq[256];
    ls[tid] = s; lq[tid] = q;
    __syncthreads();
    if (half == 0) {
        atomicAdd(&colsum[h], ls[tid] + ls[tid + 128]);
        atomicAdd(&colsq[h], lq[tid] + lq[tid + 128]);
    }
}

// both BN-param computations in one launch: blockIdx.x = which (0/1)
__global__ void k_bnp2(const float* __restrict__ cs, const float* __restrict__ gamma,
                       const float* __restrict__ beta, float* __restrict__ scout, float invn) {
    int which = blockIdx.x;
    int h = threadIdx.x;
    float mu = cs[which * 256 + h] * invn;
    float var = cs[which * 256 + 128 + h] * invn - mu * mu;
    float sc = gamma[which * HH + h] * rsqrtf(var + 1.0f);
    scout[which * 256 + h] = sc;
    scout[which * 256 + 128 + h] = beta[which * HH + h] - mu * sc;
}

// ---------------- final FC: 64-row LDS tile, BN+leaky applied ONCE during staging ----------------
__global__ __launch_bounds__(256) void k_fc(const float* __restrict__ X0, const float* __restrict__ X1,
                                            const float* __restrict__ sc0, const float* __restrict__ sc1,
                                            const float* __restrict__ Wall, const float* __restrict__ ball,
                                            float* __restrict__ out, int nrows) {
    __shared__ float Xl[64 * 132];   // 33 KB
    __shared__ float Wl[HH * CC];    // 8 KB
    __shared__ float bl[CC];
    __shared__ float scl[HH], sfl[HH];
    int which = blockIdx.y;
    const float* X = which ? X1 : X0;
    const float* scp = which ? sc1 : sc0;
    const float* W = Wall + which * HH * CC;
    float* o = out + (size_t)which * NN * CC;
    int tid = threadIdx.x;
    int row0 = blockIdx.x * 64;
    for (int i = tid * 4; i < HH * CC; i += 1024)
        *(float4*)&Wl[i] = *(const float4*)&W[i];
    if (tid < CC) bl[tid] = ball[which * CC + tid];
    if (tid < HH) { scl[tid] = scp[tid]; sfl[tid] = scp[128 + tid]; }
    __syncthreads();
    for (int idx = tid; idx < 2048; idx += 256) {
        int r = idx >> 5, cc = idx & 31;
        int n = row0 + r;
        float4 v = make_float4(0.f, 0.f, 0.f, 0.f);
        if (n < nrows) v = *(const float4*)&X[(size_t)n * HH + cc * 4];
        float4 sc = *(const float4*)&scl[cc * 4];
        float4 sf = *(const float4*)&sfl[cc * 4];
        v.x = v.x * sc.x + sf.x; v.y = v.y * sc.y + sf.y;
        v.z = v.z * sc.z + sf.z; v.w = v.w * sc.w + sf.w;
        v.x = v.x >= 0.f ? v.x : 0.01f * v.x;
        v.y = v.y >= 0.f ? v.y : 0.01f * v.y;
        v.z = v.z >= 0.f ? v.z : 0.01f * v.z;
        v.w = v.w >= 0.f ? v.w : 0.01f * v.w;
        *(float4*)&Xl[r * 132 + cc * 4] = v;
    }
    __syncthreads();
    int c = tid & 15, nl = tid >> 4;
    const float* x0 = &Xl[(nl + 0) * 132];
    const float* x1 = &Xl[(nl + 16) * 132];
    const float* x2 = &Xl[(nl + 32) * 132];
    const float* x3 = &Xl[(nl + 48) * 132];
    float a0 = bl[c], a1 = a0, a2 = a0, a3 = a0;
#pragma unroll 8
    for (int h = 0; h < HH; ++h) {
        float w = Wl[h * CC + c];
        a0 += x0[h] * w;
        a1 += x1[h] * w;
        a2 += x2[h] * w;
        a3 += x3[h] * w;
    }
    int n0 = row0 + nl;
    if (n0 < nrows) o[(size_t)n0 * CC + c] = a0;
    if (n0 + 16 < nrows) o[(size_t)(n0 + 16) * CC + c] = a1;
    if (n0 + 32 < nrows) o[(size_t)(n0 + 32) * CC + c] = a2;
    if (n0 + 48 < nrows) o[(size_t)(n0 + 48) * CC + c] = a3;
}

extern "C" void kernel_launch(void* const* d_in, const int* in_sizes, int n_in,
                              void* d_out, int out_size, void* d_ws, size_t ws_size,
                              hipStream_t stream) {
    const float* xA = (const float*)d_in[0];
    const float* xB = (const float*)d_in[1];
    const float* Wsrc = (const float*)d_in[2];
    const float* bsrc = (const float*)d_in[3];
    const float* Wdst = (const float*)d_in[4];
    const float* bdst = (const float*)d_in[5];
    const float* Wupd = (const float*)d_in[6];
    const float* bupd = (const float*)d_in[7];
    const float* attnW1 = (const float*)d_in[8];
    const float* attnb1 = (const float*)d_in[9];
    const float* attnw2 = (const float*)d_in[10];
    const float* gamma = (const float*)d_in[11];
    const float* beta = (const float*)d_in[12];
    const float* fcW = (const float*)d_in[13];
    const float* fcb = (const float*)d_in[14];
    const int* eAB = (const int*)d_in[15];
    const int* eBB = (const int*)d_in[16];
    const int* eBA = (const int*)d_in[17];
    float* out = (float*)d_out;

    // workspace layout == round-16 passing footprint
    float* ws = (float*)d_ws;
    const size_t NH = (size_t)NN * HH;
    const size_t LRHH = (size_t)LL * RR * HH * HH;
    const size_t LAH = (size_t)LL * AAA * HH;
    float* B0 = ws;
    float* B1 = B0 + NH;
    float* B2 = B1 + NH;
    float* B3 = B2 + NH;
    u16* uWdh = (u16*)(B3 + NH);
    u16* uWdl = uWdh + LRHH;
    u16* uWsh = uWdl + LRHH;
    u16* uWsl = uWsh + LRHH;
    u16* uA1h = uWsl + LRHH;        // L*AAA*HH
    u16* uA1l = uA1h + LAH;
    float* fB = (float*)(uA1l + LAH);
    float* csA = fB + LL * RR * HH;  // [sumA|sqA|sumB|sqB] 512
    float* csB = csA + 256;
    float* scA = csB + 256;          // [scA|sfA|scB|sfB] 512
    float* scB = scA + 256;
    float* scA2 = scB + 256;         // layer-1 head scales
    float* scB2 = scA2 + 256;
    float* P1 = scB2 + 256;
    float* P2 = P1 + 1024;
    float* alp = P2 + 1024;
    int* icnt = (int*)(alp + 64);
    int* irs = icnt + 3 * NN;
    int* icsr = irs + 3 * NN;
    int* ifill = icsr + 3 * EE;     // unused (layout stability)
    int* ibsum = ifill + 3 * NN;
    int* pose = (int*)B3;           // 3*EE ints; B3 unused until layer 1
    const float invN = 1.0f / (float)NN;

    k_fuse_w<<<LL * RR * HH, 256, 0, stream>>>(Wsrc, Wdst, Wupd, uWdh, uWdl, uWsh, uWsl);
    k_fuse_b<<<LL * RR, HH, 0, stream>>>(bsrc, bdst, bupd, Wupd, fB);
    k_fuse_a<<<LL * AAA, HH, 0, stream>>>(attnW1, uA1h, uA1l);

    // CSR build
    hipMemsetAsync(icnt, 0, 3 * NN * 4, stream);
    k_count<<<dim3((EE + 255) / 256, 3), 256, 0, stream>>>(eAB, eBB, eBA, icnt, pose);
    k_scan1<<<dim3(SCAN_B, 3), 256, 0, stream>>>(icnt, irs, ibsum);
    k_scan2<<<3, 128, 0, stream>>>(ibsum);
    k_scan3<<<dim3((NN + 255) / 256, 3), 256, 0, stream>>>(irs, ibsum);
    k_fill<<<dim3((EE + 255) / 256, 3), 256, 0, stream>>>(eAB, eBB, eBA, pose, irs, icsr);

    const int GEMM_GRID = (NN + 127) / 128;
    const int AGGR_GRID = (NN + 15) / 16;

    // ================= layer 0: 3 independent convs batched =================
    hipMemsetAsync(csA, 0, 512 * 4, stream);  // csA + csB
    k_aggr<<<dim3(AGGR_GRID, 3), 256, 0, stream>>>(
        (u16*)B0, (u16*)B1, (u16*)B2, xA, xB, xB,
        nullptr, nullptr, nullptr, irs, icnt, icsr, 0);
    k_cgemm<<<dim3(GEMM_GRID, 3), 256, 0, stream>>>(
        B0, B1, B2, xB, xB, xA, uWsh, uWsl, uWdh, uWdl, fB, 0,
        nullptr, nullptr, nullptr, nullptr, nullptr, csA, NN);
    k_attn<<<2 * ATTN_GRID, 256, 0, stream>>>(B0, B1, uA1h, uA1l, attnb1, attnw2, P1, P2, NN);
    k_alpha<<<1, 256, 0, stream>>>(P1, P2, alp, ATTN_GRID, invN);
    k_comb<<<512, 256, 0, stream>>>(B0, B1, alp, csB, csB + 128, NN);  // xB_new -> B0 (+stats)
    k_bnp2<<<2, 128, 0, stream>>>(csA, gamma + 0 * HH, beta + 0 * HH, scA, invN);
    // B2/B0 stay pre-BN; scA/scB applied by layer-1 consumers.

    // ================= layer 1 =================
    hipMemsetAsync(csA, 0, 512 * 4, stream);  // csA + csB
    k_aggr<<<dim3(AGGR_GRID, 2), 256, 0, stream>>>(
        (u16*)B1, (u16*)B3, nullptr, B2, B0, nullptr,
        scA, scB, nullptr, irs, icnt, icsr, 0);
    k_cgemm<<<dim3(GEMM_GRID, 2), 256, 0, stream>>>(
        B1, B3, nullptr, B0, B0, nullptr, uWsh, uWsl, uWdh, uWdl, fB, 3,
        scB, scB, nullptr, nullptr, nullptr, nullptr, NN);
    k_attn<<<2 * ATTN_GRID, 256, 0, stream>>>(B1, B3, uA1h + (size_t)AAA * HH,
                                              uA1l + (size_t)AAA * HH,
                                              attnb1 + AAA, attnw2 + AAA, P1, P2, NN);
    k_alpha<<<1, 256, 0, stream>>>(P1, P2, alp, ATTN_GRID, invN);
    k_comb<<<512, 256, 0, stream>>>(B1, B3, alp, csB, csB + 128, NN);  // xB_new -> B1 (+stats)
    k_aggr<<<dim3(AGGR_GRID, 1), 256, 0, stream>>>(
        (u16*)B3, nullptr, nullptr, B0, nullptr, nullptr,
        scB, nullptr, nullptr, irs, icnt, icsr, 2);
    k_cgemm<<<dim3(GEMM_GRID, 1), 256, 0, stream>>>(
        B3, nullptr, nullptr, B2, nullptr, nullptr, uWsh, uWsl, uWdh, uWdl, fB, 5,
        scA, nullptr, nullptr, csA, nullptr, nullptr, NN);
    k_bnp2<<<2, 128, 0, stream>>>(csA, gamma + 2 * HH, beta + 2 * HH, scA2, invN);

    // ================= head: BN+leaky fused into FC staging =================
    k_fc<<<dim3((NN + 63) / 64, 2), 256, 0, stream>>>(B3, B1, scA2, scB2, fcW, fcb, out, NN);
}

// Round 18
// 883.919 us; speedup vs baseline: 1.0724x; 1.0724x over previous
//
#include <hip/hip_runtime.h>

#define NN 100000
#define HH 128
#define EE 600000
#define LL 2
#define RR 3
#define AAA 64
#define CC 16
#define SCAN_B 98   // 98 blocks x 1024 elems covers 100000
#define ATTN_GRID ((NN + 127) / 128)

typedef unsigned short u16;
typedef unsigned int u32;
typedef __attribute__((ext_vector_type(8))) short bf16x8;
typedef __attribute__((ext_vector_type(4))) float f32x4;

__device__ inline u16 f2bf(float f) {   // RNE f32 -> bf16
    unsigned int u = __float_as_uint(f);
    return (u16)((u + 0x7FFF + ((u >> 16) & 1)) >> 16);
}
__device__ inline float bf2f(u16 h) { return __uint_as_float((unsigned int)h << 16); }

// Packed X layout (per row: 512B, 4 chunks of 128B; chunk = 4 groups of [16B hi][16B lo],
// XOR-swizzled by row). row0 % 128 == 0 so block-local r has same r&7 as global row.
__device__ __forceinline__ int hi_off(int gi, int r) { return (gi * 32) ^ ((r & 7) << 4); }
__device__ __forceinline__ int lo_off(int gi, int r) { return (gi * 32 + 16) ^ ((r & 7) << 4); }

// async global->LDS, 16B per lane; dest must be linear (wave-uniform base + lane*16)
__device__ __forceinline__ void stage16(const void* g, void* l) {
    __builtin_amdgcn_global_load_lds((const __attribute__((address_space(1))) unsigned int*)g,
                                     (__attribute__((address_space(3))) unsigned int*)l, 16, 0, 0);
}

// ---------------- weight fusion: W transposed [n][k], split bf16 hi/lo ----------------
__global__ void k_fuse_w(const float* __restrict__ Wsrc, const float* __restrict__ Wdst,
                         const float* __restrict__ Wupd, u16* __restrict__ Wdt_hi,
                         u16* __restrict__ Wdt_lo, u16* __restrict__ Wst_hi,
                         u16* __restrict__ Wst_lo) {
    int b = blockIdx.x;
    int lr = b >> 7, i = b & 127;   // i = k index
    int t = threadIdx.x;
    int j = t & 127;                // j = n index
    const float* wu = Wupd + (size_t)lr * 2 * HH * HH;
    float acc = 0.f;
    size_t o = ((size_t)lr * HH + j) * HH + i;  // transposed store [n=j][k=i]
    if (t < 128) {
        const float* wd = Wdst + ((size_t)lr * HH + i) * HH;
        for (int k = 0; k < HH; ++k) acc += wd[k] * wu[k * HH + j];
        u16 h = f2bf(acc);
        Wdt_hi[o] = h;
        Wdt_lo[o] = f2bf(acc - bf2f(h));
    } else {
        const float* wsc = Wsrc + ((size_t)lr * HH + i) * HH;
        for (int k = 0; k < HH; ++k) acc += wsc[k] * wu[(HH + k) * HH + j];
        u16 h = f2bf(acc);
        Wst_hi[o] = h;
        Wst_lo[o] = f2bf(acc - bf2f(h));
    }
}

__global__ void k_fuse_b(const float* __restrict__ bsrc, const float* __restrict__ bdst,
                         const float* __restrict__ bupd, const float* __restrict__ Wupd,
                         float* __restrict__ fB) {
    int lr = blockIdx.x;
    int j = threadIdx.x;
    const float* wu = Wupd + (size_t)lr * 2 * HH * HH;
    const float* bd = bdst + lr * HH;
    const float* bs = bsrc + lr * HH;
    float acc = bupd[lr * HH + j];
    for (int k = 0; k < HH; ++k)
        acc += bd[k] * wu[k * HH + j] + bs[k] * wu[(HH + k) * HH + j];
    fB[lr * HH + j] = acc;
}

// attnW1 [L][H][A] -> transposed [L][A][H] bf16 hi/lo (for MFMA B-frags)
__global__ void k_fuse_a(const float* __restrict__ W1, u16* __restrict__ Ah,
                         u16* __restrict__ Al) {
    int b = blockIdx.x;            // l*AAA + a
    int l = b >> 6, a = b & 63;
    int k = threadIdx.x;           // 128 threads
    float v = W1[((size_t)l * HH + k) * AAA + a];
    u16 h = f2bf(v);
    size_t o = (size_t)b * HH + k;
    Ah[o] = h;
    Al[o] = f2bf(v - bf2f(h));
}

// ---------------- CSR build: batched over 3 relations; count stores per-edge slot ----------------
__global__ void k_count(const int* __restrict__ e0, const int* __restrict__ e1,
                        const int* __restrict__ e2, int* __restrict__ cnt,
                        int* __restrict__ pose) {
    int rel = blockIdx.y;
    const int* d = (rel == 0 ? e0 : rel == 1 ? e1 : e2) + EE;
    int i = blockIdx.x * 256 + threadIdx.x;
    if (i < EE) pose[rel * EE + i] = atomicAdd(&cnt[rel * NN + d[i]], 1);
}

__global__ void k_scan1(const int* __restrict__ cnt_all, int* __restrict__ rs_all,
                        int* __restrict__ bsum) {
    __shared__ int sd[256];
    int rel = blockIdx.y;
    const int* cnt = cnt_all + rel * NN;
    int* rs = rs_all + rel * NN;
    int blk = blockIdx.x, tid = threadIdx.x;
    int base = blk * 1024 + tid * 4;
    int c0 = 0, c1 = 0, c2 = 0, c3 = 0;
    if (base + 0 < NN) c0 = cnt[base + 0];
    if (base + 1 < NN) c1 = cnt[base + 1];
    if (base + 2 < NN) c2 = cnt[base + 2];
    if (base + 3 < NN) c3 = cnt[base + 3];
    int s = c0 + c1 + c2 + c3;
    sd[tid] = s;
    __syncthreads();
    for (int off = 1; off < 256; off <<= 1) {
        int v = (tid >= off) ? sd[tid - off] : 0;
        __syncthreads();
        sd[tid] += v;
        __syncthreads();
    }
    int excl = sd[tid] - s;
    if (tid == 255) bsum[rel * 128 + blk] = sd[255];
    if (base + 0 < NN) rs[base + 0] = excl;
    if (base + 1 < NN) rs[base + 1] = excl + c0;
    if (base + 2 < NN) rs[base + 2] = excl + c0 + c1;
    if (base + 3 < NN) rs[base + 3] = excl + c0 + c1 + c2;
}

__global__ void k_scan2(int* __restrict__ bsum) {  // grid = 3, 128 threads
    __shared__ int sd[128];
    int rel = blockIdx.x;
    int tid = threadIdx.x;
    int v = (tid < SCAN_B) ? bsum[rel * 128 + tid] : 0;
    sd[tid] = v;
    __syncthreads();
    for (int off = 1; off < 128; off <<= 1) {
        int u = (tid >= off) ? sd[tid - off] : 0;
        __syncthreads();
        sd[tid] += u;
        __syncthreads();
    }
    if (tid < SCAN_B) bsum[rel * 128 + tid] = sd[tid] - v;  // exclusive
}

__global__ void k_scan3(int* __restrict__ rs_all, const int* __restrict__ bsum) {
    int rel = blockIdx.y;
    int i = blockIdx.x * 256 + threadIdx.x;
    if (i < NN) rs_all[rel * NN + i] += bsum[rel * 128 + (i >> 10)];
}

// atomic-free scatter: slot precomputed by k_count
__global__ void k_fill(const int* __restrict__ e0, const int* __restrict__ e1,
                       const int* __restrict__ e2, const int* __restrict__ pose,
                       const int* __restrict__ rs_all, int* __restrict__ csr_all) {
    int rel = blockIdx.y;
    const int* e = rel == 0 ? e0 : rel == 1 ? e1 : e2;
    int i = blockIdx.x * 256 + threadIdx.x;
    if (i >= EE) return;
    int s = e[i], d = e[EE + i];
    csr_all[(size_t)rel * EE + rs_all[rel * NN + d] + pose[rel * EE + i]] = s;
}

// ---------------- aggregation: FOUR nodes per wave (16 lanes/node, 32B/lane) ----------------
__global__ __launch_bounds__(256) void k_aggr(u16* d0, u16* d1, u16* d2,
                                              const float* s0, const float* s1, const float* s2,
                                              const float* bn0, const float* bn1, const float* bn2,
                                              const int* __restrict__ irs, const int* __restrict__ icnt,
                                              const int* __restrict__ icsr, int rel0) {
    int y = blockIdx.y;
    u16* Xp = y == 0 ? d0 : (y == 1 ? d1 : d2);
    const float* xs = y == 0 ? s0 : (y == 1 ? s1 : s2);
    const float* bnsc = y == 0 ? bn0 : (y == 1 ? bn1 : bn2);
    int rel = rel0 + y;
    const int* rs = irs + rel * NN;
    const int* cnt = icnt + rel * NN;
    const int* csr = icsr + (size_t)rel * EE;

    int node = blockIdx.x * 16 + (threadIdx.x >> 4);
    if (node >= NN) return;
    int l = threadIdx.x & 15;
    int beg = rs[node], deg = cnt[node];
    const float4* xs4 = (const float4*)xs;
    bool bn = bnsc != nullptr;
    float4 sca = make_float4(1.f, 1.f, 1.f, 1.f), scb = sca;
    float4 sfa = make_float4(0.f, 0.f, 0.f, 0.f), sfb = sfa;
    if (bn) {
        sca = *(const float4*)&bnsc[l * 8];
        scb = *(const float4*)&bnsc[l * 8 + 4];
        sfa = *(const float4*)&bnsc[128 + l * 8];
        sfb = *(const float4*)&bnsc[128 + l * 8 + 4];
    }
    auto xfa = [&](float4 v) {
        if (bn) {
            v.x = v.x * sca.x + sfa.x; v.y = v.y * sca.y + sfa.y;
            v.z = v.z * sca.z + sfa.z; v.w = v.w * sca.w + sfa.w;
            v.x = v.x >= 0.f ? v.x : 0.01f * v.x;
            v.y = v.y >= 0.f ? v.y : 0.01f * v.y;
            v.z = v.z >= 0.f ? v.z : 0.01f * v.z;
            v.w = v.w >= 0.f ? v.w : 0.01f * v.w;
        }
        return v;
    };
    auto xfb = [&](float4 v) {
        if (bn) {
            v.x = v.x * scb.x + sfb.x; v.y = v.y * scb.y + sfb.y;
            v.z = v.z * scb.z + sfb.z; v.w = v.w * scb.w + sfb.w;
            v.x = v.x >= 0.f ? v.x : 0.01f * v.x;
            v.y = v.y >= 0.f ? v.y : 0.01f * v.y;
            v.z = v.z >= 0.f ? v.z : 0.01f * v.z;
            v.w = v.w >= 0.f ? v.w : 0.01f * v.w;
        }
        return v;
    };
    float4 aA = make_float4(0.f, 0.f, 0.f, 0.f), aB = aA;
    auto addA = [&](float4 v) { aA.x += v.x; aA.y += v.y; aA.z += v.z; aA.w += v.w; };
    auto addB = [&](float4 v) { aB.x += v.x; aB.y += v.y; aB.z += v.z; aB.w += v.w; };
    int j = 0;
    for (; j + 4 <= deg; j += 4) {
        int q0 = csr[beg + j], q1 = csr[beg + j + 1];
        int q2 = csr[beg + j + 2], q3 = csr[beg + j + 3];
        float4 a0 = xfa(xs4[(size_t)q0 * 32 + 2 * l]);
        float4 b0 = xfb(xs4[(size_t)q0 * 32 + 2 * l + 1]);
        float4 a1 = xfa(xs4[(size_t)q1 * 32 + 2 * l]);
        float4 b1 = xfb(xs4[(size_t)q1 * 32 + 2 * l + 1]);
        float4 a2 = xfa(xs4[(size_t)q2 * 32 + 2 * l]);
        float4 b2 = xfb(xs4[(size_t)q2 * 32 + 2 * l + 1]);
        float4 a3 = xfa(xs4[(size_t)q3 * 32 + 2 * l]);
        float4 b3 = xfb(xs4[(size_t)q3 * 32 + 2 * l + 1]);
        aA.x += (a0.x + a1.x) + (a2.x + a3.x);
        aA.y += (a0.y + a1.y) + (a2.y + a3.y);
        aA.z += (a0.z + a1.z) + (a2.z + a3.z);
        aA.w += (a0.w + a1.w) + (a2.w + a3.w);
        aB.x += (b0.x + b1.x) + (b2.x + b3.x);
        aB.y += (b0.y + b1.y) + (b2.y + b3.y);
        aB.z += (b0.z + b1.z) + (b2.z + b3.z);
        aB.w += (b0.w + b1.w) + (b2.w + b3.w);
    }
    if (j + 2 <= deg) {
        int q0 = csr[beg + j], q1 = csr[beg + j + 1];
        float4 a0 = xfa(xs4[(size_t)q0 * 32 + 2 * l]);
        float4 b0 = xfb(xs4[(size_t)q0 * 32 + 2 * l + 1]);
        float4 a1 = xfa(xs4[(size_t)q1 * 32 + 2 * l]);
        float4 b1 = xfb(xs4[(size_t)q1 * 32 + 2 * l + 1]);
        aA.x += a0.x + a1.x; aA.y += a0.y + a1.y;
        aA.z += a0.z + a1.z; aA.w += a0.w + a1.w;
        aB.x += b0.x + b1.x; aB.y += b0.y + b1.y;
        aB.z += b0.z + b1.z; aB.w += b0.w + b1.w;
        j += 2;
    }
    if (j < deg) {
        int q0 = csr[beg + j];
        addA(xfa(xs4[(size_t)q0 * 32 + 2 * l]));
        addB(xfb(xs4[(size_t)q0 * 32 + 2 * l + 1]));
    }
    float sc = 1.0f / fmaxf((float)deg, 1.0f);
    float v0 = aA.x * sc, v1 = aA.y * sc, v2 = aA.z * sc, v3 = aA.w * sc;
    float v4 = aB.x * sc, v5 = aB.y * sc, v6 = aB.z * sc, v7 = aB.w * sc;
    u16 h0 = f2bf(v0), h1 = f2bf(v1), h2 = f2bf(v2), h3 = f2bf(v3);
    u16 h4 = f2bf(v4), h5 = f2bf(v5), h6 = f2bf(v6), h7 = f2bf(v7);
    bf16x8 hv = {(short)h0, (short)h1, (short)h2, (short)h3,
                 (short)h4, (short)h5, (short)h6, (short)h7};
    bf16x8 lv = {(short)f2bf(v0 - bf2f(h0)), (short)f2bf(v1 - bf2f(h1)),
                 (short)f2bf(v2 - bf2f(h2)), (short)f2bf(v3 - bf2f(h3)),
                 (short)f2bf(v4 - bf2f(h4)), (short)f2bf(v5 - bf2f(h5)),
                 (short)f2bf(v6 - bf2f(h6)), (short)f2bf(v7 - bf2f(h7))};
    int gi = l & 3;
    char* base = (char*)Xp + (size_t)node * 512 + (l >> 2) * 128;
    __builtin_nontemporal_store(hv, (bf16x8*)(base + hi_off(gi, node)));
    __builtin_nontemporal_store(lv, (bf16x8*)(base + lo_off(gi, node)));
}

// ---------------- fused conv GEMM, batched over up to 3 relations (blockIdx.y) ----------------
// Y = X1@Wsrc' + X2@Wdst' + bias via bf16x3 MFMA; chunk-level double-buffered LDS.
// Epilogue bounces through LDS (Xt reused as [64][128] f32) for full-line coalesced writes.
__global__ __launch_bounds__(256) void k_cgemm(float* Y0, float* Y1, float* Y2,
                                               const float* X20, const float* X21, const float* X22,
                                               const u16* __restrict__ Wsh, const u16* __restrict__ Wsl,
                                               const u16* __restrict__ Wdh, const u16* __restrict__ Wdl,
                                               const float* __restrict__ fB, int lr0,
                                               const float* bn0, const float* bn1, const float* bn2,
                                               float* cs0, float* cs1, float* cs2, int nrows) {
    __shared__ __attribute__((aligned(16))) char Xt[2][16384];
    int y = blockIdx.y;
    float* Y = y == 0 ? Y0 : (y == 1 ? Y1 : Y2);
    const u16* X1p = (const u16*)Y;
    const float* X2 = y == 0 ? X20 : (y == 1 ? X21 : X22);
    const float* bnsc2 = y == 0 ? bn0 : (y == 1 ? bn1 : bn2);
    float* colsum = y == 0 ? cs0 : (y == 1 ? cs1 : cs2);
    int lr = lr0 + y;
    const u16* W1h = Wsh + (size_t)lr * HH * HH;
    const u16* W1l = Wsl + (size_t)lr * HH * HH;
    const u16* W2h = Wdh + (size_t)lr * HH * HH;
    const u16* W2l = Wdl + (size_t)lr * HH * HH;
    const float* bias = fB + lr * HH;

    int tid = threadIdx.x;
    int row0 = blockIdx.x * 128;
    int lane = tid & 63, wv = tid >> 6;
    int l15 = lane & 15, lg = lane >> 4;
    bool full = (row0 + 128 <= nrows);

    f32x4 acc[8][2];
#pragma unroll
    for (int i = 0; i < 8; ++i)
#pragma unroll
        for (int j = 0; j < 2; ++j) acc[i][j] = (f32x4)(0.f);

    auto stage_chunk = [&](int c) {
        char* dst = Xt[c & 1];
        if (c < 4) {
#pragma unroll
            for (int p = 0; p < 4; ++p) {
                int tb = p * 4096 + tid * 16;
                int r = tb >> 7, off = tb & 127;
                stage16((const char*)X1p + (size_t)(row0 + r) * 512 + (c & 3) * 128 + off,
                        dst + tb);
            }
        } else {
            int kc = (c & 3) * 32;
#pragma unroll
            for (int it = 0; it < 2; ++it) {
                int g2 = tid + it * 256;
                int r = g2 >> 2, gi = g2 & 3;
                float4 a = make_float4(0.f, 0.f, 0.f, 0.f), b = a;
                if (full || row0 + r < nrows) {
                    const float* xp = &X2[(size_t)(row0 + r) * HH + kc + gi * 8];
                    a = *(const float4*)xp;
                    b = *(const float4*)(xp + 4);
                }
                if (bnsc2) {
                    const float* scp = bnsc2 + kc + gi * 8;
                    const float* sfp = bnsc2 + 128 + kc + gi * 8;
                    float4 s0 = *(const float4*)scp, s1 = *(const float4*)(scp + 4);
                    float4 f0 = *(const float4*)sfp, f1 = *(const float4*)(sfp + 4);
                    a.x = a.x * s0.x + f0.x; a.y = a.y * s0.y + f0.y;
                    a.z = a.z * s0.z + f0.z; a.w = a.w * s0.w + f0.w;
                    b.x = b.x * s1.x + f1.x; b.y = b.y * s1.y + f1.y;
                    b.z = b.z * s1.z + f1.z; b.w = b.w * s1.w + f1.w;
                    a.x = a.x >= 0.f ? a.x : 0.01f * a.x;
                    a.y = a.y >= 0.f ? a.y : 0.01f * a.y;
                    a.z = a.z >= 0.f ? a.z : 0.01f * a.z;
                    a.w = a.w >= 0.f ? a.w : 0.01f * a.w;
                    b.x = b.x >= 0.f ? b.x : 0.01f * b.x;
                    b.y = b.y >= 0.f ? b.y : 0.01f * b.y;
                    b.z = b.z >= 0.f ? b.z : 0.01f * b.z;
                    b.w = b.w >= 0.f ? b.w : 0.01f * b.w;
                }
                u16 h0 = f2bf(a.x), h1 = f2bf(a.y), h2 = f2bf(a.z), h3 = f2bf(a.w);
                u16 h4 = f2bf(b.x), h5 = f2bf(b.y), h6 = f2bf(b.z), h7 = f2bf(b.w);
                bf16x8 hv = {(short)h0, (short)h1, (short)h2, (short)h3,
                             (short)h4, (short)h5, (short)h6, (short)h7};
                bf16x8 lv = {(short)f2bf(a.x - bf2f(h0)), (short)f2bf(a.y - bf2f(h1)),
                             (short)f2bf(a.z - bf2f(h2)), (short)f2bf(a.w - bf2f(h3)),
                             (short)f2bf(b.x - bf2f(h4)), (short)f2bf(b.y - bf2f(h5)),
                             (short)f2bf(b.z - bf2f(h6)), (short)f2bf(b.w - bf2f(h7))};
                char* rb = dst + r * 128;
                *(bf16x8*)(rb + hi_off(gi, r)) = hv;
                *(bf16x8*)(rb + lo_off(gi, r)) = lv;
            }
        }
    };

    stage_chunk(0);
#pragma unroll
    for (int c = 0; c < 8; ++c) {
        const u16* Wh = (c < 4) ? W1h : W2h;
        const u16* Wl = (c < 4) ? W1l : W2l;
        int kc = (c & 3) * 32;
        bf16x8 bh[2], bl[2];
#pragma unroll
        for (int nt = 0; nt < 2; ++nt) {
            int n = (wv * 2 + nt) * 16 + l15;
            bh[nt] = *(const bf16x8*)&Wh[(size_t)n * HH + kc + lg * 8];
            bl[nt] = *(const bf16x8*)&Wl[(size_t)n * HH + kc + lg * 8];
        }
        __syncthreads();  // chunk c staged & chunk c-1 fully consumed
        if (c < 7) stage_chunk(c + 1);  // overlaps with MFMA below
        const char* buf = Xt[c & 1];
#pragma unroll
        for (int mt = 0; mt < 8; ++mt) {
            int r = mt * 16 + l15;
            const char* rb = buf + r * 128;
            bf16x8 ah = *(const bf16x8*)(rb + hi_off(lg, r));
            bf16x8 al = *(const bf16x8*)(rb + lo_off(lg, r));
#pragma unroll
            for (int nt = 0; nt < 2; ++nt) {
                acc[mt][nt] = __builtin_amdgcn_mfma_f32_16x16x32_bf16(ah, bh[nt], acc[mt][nt], 0, 0, 0);
                acc[mt][nt] = __builtin_amdgcn_mfma_f32_16x16x32_bf16(ah, bl[nt], acc[mt][nt], 0, 0, 0);
                acc[mt][nt] = __builtin_amdgcn_mfma_f32_16x16x32_bf16(al, bh[nt], acc[mt][nt], 0, 0, 0);
            }
        }
    }
    // ---- epilogue: bounce acc through LDS (Xt free) -> full-line coalesced writes ----
    float* Lf = (float*)Xt;   // 32KB = [64][128] f32
    float bv0 = bias[(wv * 2 + 0) * 16 + l15];
    float bv1 = bias[(wv * 2 + 1) * 16 + l15];
    float ss0 = 0.f, sq0 = 0.f, ss1 = 0.f, sq1 = 0.f;
#pragma unroll
    for (int p = 0; p < 2; ++p) {
        __syncthreads();  // all K-loop LDS reads done / previous pass consumed
#pragma unroll
        for (int m4 = 0; m4 < 4; ++m4) {
            int mt = p * 4 + m4;
#pragma unroll
            for (int nt = 0; nt < 2; ++nt) {
                int ncol = (wv * 2 + nt) * 16 + l15;
                float bv = nt ? bv1 : bv0;
#pragma unroll
                for (int j = 0; j < 4; ++j) {
                    int lr_ = m4 * 16 + lg * 4 + j;
                    float yv = acc[mt][nt][j] + bv;
                    Lf[lr_ * 128 + ncol] = yv;
                    if (row0 + p * 64 + lr_ < nrows) {
                        if (nt) { ss1 += yv; sq1 += yv * yv; }
                        else    { ss0 += yv; sq0 += yv * yv; }
                    }
                }
            }
        }
        __syncthreads();
#pragma unroll
        for (int k = 0; k < 8; ++k) {
            int fi = (tid + k * 256) * 4;
            int lr_ = fi >> 7, col = fi & 127;
            int r = row0 + p * 64 + lr_;
            if (r < nrows)
                *(float4*)&Y[(size_t)r * HH + col] = *(const float4*)&Lf[lr_ * 128 + col];
        }
    }
    if (colsum) {
#pragma unroll
        for (int nt = 0; nt < 2; ++nt) {
            float s = nt ? ss1 : ss0;
            float q = nt ? sq1 : sq0;
            s += __shfl_xor(s, 16); s += __shfl_xor(s, 32);
            q += __shfl_xor(q, 16); q += __shfl_xor(q, 32);
            if (lg == 0) {
                int ncol = (wv * 2 + nt) * 16 + l15;
                atomicAdd(&colsum[ncol], s);
                atomicAdd(&colsum[128 + ncol], q);
            }
        }
    }
}

// ---------------- attention score: bf16x3 MFMA S = X@W1, tanh, dot w2, block-sum ----------------
__global__ __launch_bounds__(256) void k_attn(const float* __restrict__ XA, const float* __restrict__ XB,
                                              const u16* __restrict__ Ah, const u16* __restrict__ Al,
                                              const float* __restrict__ b1, const float* __restrict__ w2,
                                              float* __restrict__ PA, float* __restrict__ PB, int nrows) {
    __shared__ __attribute__((aligned(16))) char Xt[2][16384];
    __shared__ float red[4];
    int tid = threadIdx.x;
    bool second = blockIdx.x >= ATTN_GRID;
    const float* X = second ? XB : XA;
    float* partial = second ? PB : PA;
    int row0 = (second ? blockIdx.x - ATTN_GRID : blockIdx.x) * 128;
    int lane = tid & 63, wv = tid >> 6;
    int l15 = lane & 15, lg = lane >> 4;
    bool full = (row0 + 128 <= nrows);

    f32x4 acc[8];
#pragma unroll
    for (int i = 0; i < 8; ++i) acc[i] = (f32x4)(0.f);

    auto stage_chunk = [&](int c) {
        char* dst = Xt[c & 1];
        int kc = c * 32;
#pragma unroll
        for (int it = 0; it < 2; ++it) {
            int g2 = tid + it * 256;
            int r = g2 >> 2, gi = g2 & 3;
            float4 a = make_float4(0.f, 0.f, 0.f, 0.f), b = a;
            if (full || row0 + r < nrows) {
                const float* xp = &X[(size_t)(row0 + r) * HH + kc + gi * 8];
                a = *(const float4*)xp;
                b = *(const float4*)(xp + 4);
            }
            u16 h0 = f2bf(a.x), h1 = f2bf(a.y), h2 = f2bf(a.z), h3 = f2bf(a.w);
            u16 h4 = f2bf(b.x), h5 = f2bf(b.y), h6 = f2bf(b.z), h7 = f2bf(b.w);
            bf16x8 hv = {(short)h0, (short)h1, (short)h2, (short)h3,
                         (short)h4, (short)h5, (short)h6, (short)h7};
            bf16x8 lv = {(short)f2bf(a.x - bf2f(h0)), (short)f2bf(a.y - bf2f(h1)),
                         (short)f2bf(a.z - bf2f(h2)), (short)f2bf(a.w - bf2f(h3)),
                         (short)f2bf(b.x - bf2f(h4)), (short)f2bf(b.y - bf2f(h5)),
                         (short)f2bf(b.z - bf2f(h6)), (short)f2bf(b.w - bf2f(h7))};
            char* rb = dst + r * 128;
            *(bf16x8*)(rb + hi_off(gi, r)) = hv;
            *(bf16x8*)(rb + lo_off(gi, r)) = lv;
        }
    };

    stage_chunk(0);
#pragma unroll
    for (int c = 0; c < 4; ++c) {
        int kc = c * 32;
        int a = wv * 16 + l15;
        bf16x8 bh = *(const bf16x8*)&Ah[(size_t)a * HH + kc + lg * 8];
        bf16x8 bl = *(const bf16x8*)&Al[(size_t)a * HH + kc + lg * 8];
        __syncthreads();
        if (c < 3) stage_chunk(c + 1);
        const char* buf = Xt[c & 1];
#pragma unroll
        for (int mt = 0; mt < 8; ++mt) {
            int r = mt * 16 + l15;
            const char* rb = buf + r * 128;
            bf16x8 ah = *(const bf16x8*)(rb + hi_off(lg, r));
            bf16x8 al = *(const bf16x8*)(rb + lo_off(lg, r));
            acc[mt] = __builtin_amdgcn_mfma_f32_16x16x32_bf16(ah, bh, acc[mt], 0, 0, 0);
            acc[mt] = __builtin_amdgcn_mfma_f32_16x16x32_bf16(ah, bl, acc[mt], 0, 0, 0);
            acc[mt] = __builtin_amdgcn_mfma_f32_16x16x32_bf16(al, bh, acc[mt], 0, 0, 0);
        }
    }
    float b1v = b1[wv * 16 + l15];
    float w2v = w2[wv * 16 + l15];
    float tot = 0.f;
#pragma unroll
    for (int mt = 0; mt < 8; ++mt)
#pragma unroll
        for (int j = 0; j < 4; ++j) {
            int r = row0 + mt * 16 + lg * 4 + j;
            if (r < nrows) tot += tanhf(acc[mt][j] + b1v) * w2v;
        }
#pragma unroll
    for (int off = 32; off > 0; off >>= 1) tot += __shfl_xor(tot, off);
    if (lane == 0) red[wv] = tot;
    __syncthreads();
    if (tid == 0)
        partial[second ? (blockIdx.x - ATTN_GRID) : blockIdx.x] = red[0] + red[1] + red[2] + red[3];
}

__global__ void k_alpha(const float* __restrict__ P1, const float* __restrict__ P2,
                        float* __restrict__ alpha, int nparts, float invn) {
    __shared__ float s1[256], s2[256];
    int tid = threadIdx.x;
    float a = 0.f, b = 0.f;
    for (int i = tid; i < nparts; i += 256) { a += P1[i]; b += P2[i]; }
    s1[tid] = a; s2[tid] = b;
    __syncthreads();
    for (int off = 128; off > 0; off >>= 1) {
        if (tid < off) { s1[tid] += s1[tid + off]; s2[tid] += s2[tid + off]; }
        __syncthreads();
    }
    if (tid == 0) {
        float m1 = s1[0] * invn, m2 = s2[0] * invn;
        float mx = fmaxf(m1, m2);
        float e1 = expf(m1 - mx), e2 = expf(m2 - mx);
        float inv = 1.f / (e1 + e2);
        alpha[0] = e1 * inv; alpha[1] = e2 * inv;
    }
}

// ---------------- combine (attention mix) + column stats ----------------
__global__ __launch_bounds__(256) void k_comb(float* __restrict__ X, const float* __restrict__ Y,
                                              const float* __restrict__ alpha, float* __restrict__ colsum,
                                              float* __restrict__ colsq, int nrows) {
    int tid = threadIdx.x;
    int h = tid & 127, half = tid >> 7;
    float a0 = alpha[0], a1 = alpha[1];
    float s = 0.f, q = 0.f;
    for (int n = blockIdx.x * 2 + half; n < nrows; n += gridDim.x * 2) {
        size_t off = (size_t)n * HH + h;
        float v = a0 * X[off] + a1 * Y[off];
        X[off] = v;
        s += v; q += v * v;
    }
    __shared__ float ls[256], lq[256];
    ls[tid] = s; lq[tid] = q;
    __syncthreads();
    if (half == 0) {
        atomicAdd(&colsum[h], ls[tid] + ls[tid + 128]);
        atomicAdd(&colsq[h], lq[tid] + lq[tid + 128]);
    }
}

// both BN-param computations in one launch: blockIdx.x = which (0/1)
__global__ void k_bnp2(const float* __restrict__ cs, const float* __restrict__ gamma,
                       const float* __restrict__ beta, float* __restrict__ scout, float invn) {
    int which = blockIdx.x;
    int h = threadIdx.x;
    float mu = cs[which * 256 + h] * invn;
    float var = cs[which * 256 + 128 + h] * invn - mu * mu;
    float sc = gamma[which * HH + h] * rsqrtf(var + 1.0f);
    scout[which * 256 + h] = sc;
    scout[which * 256 + 128 + h] = beta[which * HH + h] - mu * sc;
}

// ---------------- final FC: 64-row LDS tile, BN+leaky applied ONCE during staging ----------------
__global__ __launch_bounds__(256) void k_fc(const float* __restrict__ X0, const float* __restrict__ X1,
                                            const float* __restrict__ sc0, const float* __restrict__ sc1,
                                            const float* __restrict__ Wall, const float* __restrict__ ball,
                                            float* __restrict__ out, int nrows) {
    __shared__ float Xl[64 * 132];   // 33 KB
    __shared__ float Wl[HH * CC];    // 8 KB
    __shared__ float bl[CC];
    __shared__ float scl[HH], sfl[HH];
    int which = blockIdx.y;
    const float* X = which ? X1 : X0;
    const float* scp = which ? sc1 : sc0;
    const float* W = Wall + which * HH * CC;
    float* o = out + (size_t)which * NN * CC;
    int tid = threadIdx.x;
    int row0 = blockIdx.x * 64;
    for (int i = tid * 4; i < HH * CC; i += 1024)
        *(float4*)&Wl[i] = *(const float4*)&W[i];
    if (tid < CC) bl[tid] = ball[which * CC + tid];
    if (tid < HH) { scl[tid] = scp[tid]; sfl[tid] = scp[128 + tid]; }
    __syncthreads();
    for (int idx = tid; idx < 2048; idx += 256) {
        int r = idx >> 5, cc = idx & 31;
        int n = row0 + r;
        float4 v = make_float4(0.f, 0.f, 0.f, 0.f);
        if (n < nrows) v = *(const float4*)&X[(size_t)n * HH + cc * 4];
        float4 sc = *(const float4*)&scl[cc * 4];
        float4 sf = *(const float4*)&sfl[cc * 4];
        v.x = v.x * sc.x + sf.x; v.y = v.y * sc.y + sf.y;
        v.z = v.z * sc.z + sf.z; v.w = v.w * sc.w + sf.w;
        v.x = v.x >= 0.f ? v.x : 0.01f * v.x;
        v.y = v.y >= 0.f ? v.y : 0.01f * v.y;
        v.z = v.z >= 0.f ? v.z : 0.01f * v.z;
        v.w = v.w >= 0.f ? v.w : 0.01f * v.w;
        *(float4*)&Xl[r * 132 + cc * 4] = v;
    }
    __syncthreads();
    int c = tid & 15, nl = tid >> 4;
    const float* x0 = &Xl[(nl + 0) * 132];
    const float* x1 = &Xl[(nl + 16) * 132];
    const float* x2 = &Xl[(nl + 32) * 132];
    const float* x3 = &Xl[(nl + 48) * 132];
    float a0 = bl[c], a1 = a0, a2 = a0, a3 = a0;
#pragma unroll 8
    for (int h = 0; h < HH; ++h) {
        float w = Wl[h * CC + c];
        a0 += x0[h] * w;
        a1 += x1[h] * w;
        a2 += x2[h] * w;
        a3 += x3[h] * w;
    }
    int n0 = row0 + nl;
    if (n0 < nrows) o[(size_t)n0 * CC + c] = a0;
    if (n0 + 16 < nrows) o[(size_t)(n0 + 16) * CC + c] = a1;
    if (n0 + 32 < nrows) o[(size_t)(n0 + 32) * CC + c] = a2;
    if (n0 + 48 < nrows) o[(size_t)(n0 + 48) * CC + c] = a3;
}

extern "C" void kernel_launch(void* const* d_in, const int* in_sizes, int n_in,
                              void* d_out, int out_size, void* d_ws, size_t ws_size,
                              hipStream_t stream) {
    const float* xA = (const float*)d_in[0];
    const float* xB = (const float*)d_in[1];
    const float* Wsrc = (const float*)d_in[2];
    const float* bsrc = (const float*)d_in[3];
    const float* Wdst = (const float*)d_in[4];
    const float* bdst = (const float*)d_in[5];
    const float* Wupd = (const float*)d_in[6];
    const float* bupd = (const float*)d_in[7];
    const float* attnW1 = (const float*)d_in[8];
    const float* attnb1 = (const float*)d_in[9];
    const float* attnw2 = (const float*)d_in[10];
    const float* gamma = (const float*)d_in[11];
    const float* beta = (const float*)d_in[12];
    const float* fcW = (const float*)d_in[13];
    const float* fcb = (const float*)d_in[14];
    const int* eAB = (const int*)d_in[15];
    const int* eBB = (const int*)d_in[16];
    const int* eBA = (const int*)d_in[17];
    float* out = (float*)d_out;

    // workspace layout == round-17 passing footprint
    float* ws = (float*)d_ws;
    const size_t NH = (size_t)NN * HH;
    const size_t LRHH = (size_t)LL * RR * HH * HH;
    const size_t LAH = (size_t)LL * AAA * HH;
    float* B0 = ws;
    float* B1 = B0 + NH;
    float* B2 = B1 + NH;
    float* B3 = B2 + NH;
    u16* uWdh = (u16*)(B3 + NH);
    u16* uWdl = uWdh + LRHH;
    u16* uWsh = uWdl + LRHH;
    u16* uWsl = uWsh + LRHH;
    u16* uA1h = uWsl + LRHH;        // L*AAA*HH
    u16* uA1l = uA1h + LAH;
    float* fB = (float*)(uA1l + LAH);
    float* csA = fB + LL * RR * HH;  // [sumA|sqA|sumB|sqB] 512
    float* csB = csA + 256;
    float* scA = csB + 256;          // [scA|sfA|scB|sfB] 512
    float* scB = scA + 256;
    float* scA2 = scB + 256;         // layer-1 head scales
    float* scB2 = scA2 + 256;
    float* P1 = scB2 + 256;
    float* P2 = P1 + 1024;
    float* alp = P2 + 1024;
    int* icnt = (int*)(alp + 64);
    int* irs = icnt + 3 * NN;
    int* icsr = irs + 3 * NN;
    int* ifill = icsr + 3 * EE;     // unused (layout stability)
    int* ibsum = ifill + 3 * NN;
    int* pose = (int*)B3;           // 3*EE ints; B3 unused until layer 1
    const float invN = 1.0f / (float)NN;

    k_fuse_w<<<LL * RR * HH, 256, 0, stream>>>(Wsrc, Wdst, Wupd, uWdh, uWdl, uWsh, uWsl);
    k_fuse_b<<<LL * RR, HH, 0, stream>>>(bsrc, bdst, bupd, Wupd, fB);
    k_fuse_a<<<LL * AAA, HH, 0, stream>>>(attnW1, uA1h, uA1l);

    // CSR build
    hipMemsetAsync(icnt, 0, 3 * NN * 4, stream);
    k_count<<<dim3((EE + 255) / 256, 3), 256, 0, stream>>>(eAB, eBB, eBA, icnt, pose);
    k_scan1<<<dim3(SCAN_B, 3), 256, 0, stream>>>(icnt, irs, ibsum);
    k_scan2<<<3, 128, 0, stream>>>(ibsum);
    k_scan3<<<dim3((NN + 255) / 256, 3), 256, 0, stream>>>(irs, ibsum);
    k_fill<<<dim3((EE + 255) / 256, 3), 256, 0, stream>>>(eAB, eBB, eBA, pose, irs, icsr);

    const int GEMM_GRID = (NN + 127) / 128;
    const int AGGR_GRID = (NN + 15) / 16;

    // ================= layer 0: 3 independent convs batched =================
    hipMemsetAsync(csA, 0, 512 * 4, stream);  // csA + csB
    k_aggr<<<dim3(AGGR_GRID, 3), 256, 0, stream>>>(
        (u16*)B0, (u16*)B1, (u16*)B2, xA, xB, xB,
        nullptr, nullptr, nullptr, irs, icnt, icsr, 0);
    k_cgemm<<<dim3(GEMM_GRID, 3), 256, 0, stream>>>(
        B0, B1, B2, xB, xB, xA, uWsh, uWsl, uWdh, uWdl, fB, 0,
        nullptr, nullptr, nullptr, nullptr, nullptr, csA, NN);
    k_attn<<<2 * ATTN_GRID, 256, 0, stream>>>(B0, B1, uA1h, uA1l, attnb1, attnw2, P1, P2, NN);
    k_alpha<<<1, 256, 0, stream>>>(P1, P2, alp, ATTN_GRID, invN);
    k_comb<<<512, 256, 0, stream>>>(B0, B1, alp, csB, csB + 128, NN);  // xB_new -> B0 (+stats)
    k_bnp2<<<2, 128, 0, stream>>>(csA, gamma + 0 * HH, beta + 0 * HH, scA, invN);
    // B2/B0 stay pre-BN; scA/scB applied by layer-1 consumers.

    // ================= layer 1 =================
    hipMemsetAsync(csA, 0, 512 * 4, stream);  // csA + csB
    k_aggr<<<dim3(AGGR_GRID, 2), 256, 0, stream>>>(
        (u16*)B1, (u16*)B3, nullptr, B2, B0, nullptr,
        scA, scB, nullptr, irs, icnt, icsr, 0);
    k_cgemm<<<dim3(GEMM_GRID, 2), 256, 0, stream>>>(
        B1, B3, nullptr, B0, B0, nullptr, uWsh, uWsl, uWdh, uWdl, fB, 3,
        scB, scB, nullptr, nullptr, nullptr, nullptr, NN);
    k_attn<<<2 * ATTN_GRID, 256, 0, stream>>>(B1, B3, uA1h + (size_t)AAA * HH,
                                              uA1l + (size_t)AAA * HH,
                                              attnb1 + AAA, attnw2 + AAA, P1, P2, NN);
    k_alpha<<<1, 256, 0, stream>>>(P1, P2, alp, ATTN_GRID, invN);
    k_comb<<<512, 256, 0, stream>>>(B1, B3, alp, csB, csB + 128, NN);  // xB_new -> B1 (+stats)
    k_aggr<<<dim3(AGGR_GRID, 1), 256, 0, stream>>>(
        (u16*)B3, nullptr, nullptr, B0, nullptr, nullptr,
        scB, nullptr, nullptr, irs, icnt, icsr, 2);
    k_cgemm<<<dim3(GEMM_GRID, 1), 256, 0, stream>>>(
        B3, nullptr, nullptr, B2, nullptr, nullptr, uWsh, uWsl, uWdh, uWdl, fB, 5,
        scA, nullptr, nullptr, csA, nullptr, nullptr, NN);
    k_bnp2<<<2, 128, 0, stream>>>(csA, gamma + 2 * HH, beta + 2 * HH, scA2, invN);

    // ================= head: BN+leaky fused into FC staging =================
    k_fc<<<dim3((NN + 63) / 64, 2), 256, 0, stream>>>(B3, B1, scA2, scB2, fcW, fcb, out, NN);
}